// Round 2
// baseline (74.211 us; speedup 1.0000x reference)
//
#include <hip/hip_runtime.h>
#include <hip/hip_bf16.h>

// ChamferDistanceMatrixL2: B=32, G=64, N=32, C=3.
// out[b][g1][g2] = mean_n min_m d + mean_m min_n d, d = s1 + s2 - 2*dot.
//
// R2: two threads per output (m-split, partners = lane^32 in the SAME wave).
//  - 262144 threads = 4096 waves -> 4 waves/SIMD (grid no longer occupancy cap)
//  - per-thread arrays: x2/y2/z2/s2[16] + colmin[16] ~= 100 VGPR (fits 128 cap)
//  - p2 fetched as 12 global_load_dwordx4 (vs 96 scalar b32 in R1): 8x fewer
//    address-divergent VMEM insts -> TA probe cost /8
//  - per-n partial row-min exchanged via one __shfl_xor(.,32): colmin stays
//    thread-local (each thread owns its 16 m's across ALL n) -> no LDS at all.
// Block 256 = 4 waves: wave w: g1 = 2*(blk&31) + (w>>1); lane: mhalf = lane>>5,
// g2 = (w&1)*32 + (lane&31). Grid = 32 b * 32 g1-pairs = 1024 blocks.

__global__ __launch_bounds__(256, 4)
void chamfer_dist_kernel(const float* __restrict__ xyz1,
                         const float* __restrict__ xyz2,
                         float* __restrict__ out) {
    const int tid  = threadIdx.x;
    const int w    = tid >> 6;                       // wave in block: 0..3
    const int lane = tid & 63;
    const int mh   = lane >> 5;                      // m-half: 0..1
    const int b    = blockIdx.x >> 5;                // 0..31
    const int g1   = ((blockIdx.x & 31) << 1) | (w >> 1);   // 0..63
    const int g2   = ((w & 1) << 5) | (lane & 31);          // 0..63

    // ---- register-cache my 16 m-points of group g2 via 12 dwordx4 ----
    const float4* __restrict__ p2v =
        (const float4*)(xyz2 + (size_t)(b * 64 + g2) * 96 + mh * 48);
    float buf[48];
#pragma unroll
    for (int i = 0; i < 12; ++i) {
        const float4 v = p2v[i];
        buf[4 * i + 0] = v.x;
        buf[4 * i + 1] = v.y;
        buf[4 * i + 2] = v.z;
        buf[4 * i + 3] = v.w;
    }
    float x2[16], y2[16], z2[16], s2[16];
#pragma unroll
    for (int j = 0; j < 16; ++j) {
        x2[j] = buf[3 * j + 0];
        y2[j] = buf[3 * j + 1];
        z2[j] = buf[3 * j + 2];
        s2[j] = fmaf(x2[j], x2[j], fmaf(y2[j], y2[j], z2[j] * z2[j]));
    }

    float colmin[16];
#pragma unroll
    for (int j = 0; j < 16; ++j) colmin[j] = 3.0e38f;

    const float* __restrict__ p1 = xyz1 + (size_t)(b * 64 + g1) * 96;
    float sum1 = 0.0f;

#pragma unroll 2
    for (int n = 0; n < 32; ++n) {
        const float x1 = p1[3 * n + 0];   // wave-uniform address -> 1 line
        const float y1 = p1[3 * n + 1];
        const float z1 = p1[3 * n + 2];
        const float s1 = fmaf(x1, x1, fmaf(y1, y1, z1 * z1));
        const float a = -2.0f * x1;
        const float c = -2.0f * y1;
        const float e = -2.0f * z1;

        float t[16];
#pragma unroll
        for (int j = 0; j < 16; ++j) {
            t[j] = fmaf(a, x2[j], fmaf(c, y2[j], fmaf(e, z2[j], s1 + s2[j])));
            colmin[j] = fminf(colmin[j], t[j]);
        }
        // pairwise tree-min over my 16 m's (short dep chain, enables v_min3)
#pragma unroll
        for (int s = 8; s > 0; s >>= 1) {
#pragma unroll
            for (int j = 0; j < s; ++j) t[j] = fminf(t[j], t[j + s]);
        }
        // merge with partner's half (lane^32, same wave) -> full row min
        const float other = __shfl_xor(t[0], 32, 64);
        sum1 += fminf(t[0], other);
    }

    // colmin is complete (my 16 m's, all n). Partial col-sum, tree.
#pragma unroll
    for (int s = 8; s > 0; s >>= 1) {
#pragma unroll
        for (int j = 0; j < s; ++j) colmin[j] += colmin[j + s];
    }
    const float sum2 = colmin[0] + __shfl_xor(colmin[0], 32, 64);

    const float res = (sum1 + sum2) * (1.0f / 32.0f);
    if (mh == 0) {
        out[(size_t)(b * 64 + g1) * 64 + g2] = res;  // lanes 0..31 -> 128B coalesced
    }
}

extern "C" void kernel_launch(void* const* d_in, const int* in_sizes, int n_in,
                              void* d_out, int out_size, void* d_ws, size_t ws_size,
                              hipStream_t stream) {
    const float* xyz1 = (const float*)d_in[0];
    const float* xyz2 = (const float*)d_in[1];
    float* out = (float*)d_out;

    dim3 grid(1024);  // 32 b * 32 g1-pairs
    dim3 block(256);  // 4 waves: (g1 sub-pair) x (g2 half), lanes = mhalf x 32 g2
    chamfer_dist_kernel<<<grid, block, 0, stream>>>(xyz1, xyz2, out);
}